// Round 4
// baseline (540.802 us; speedup 1.0000x reference)
//
#include <hip/hip_runtime.h>
#include <math.h>

#define N_NODES 50000
#define N_EDGES 800000
#define HD 128          // H*D = 4*32
#define GG 1024
#define NEG_SLOPE 0.2f
#define SCAN_B 1024
#define NB ((N_NODES + SCAN_B - 1) / SCAN_B)   // 49

typedef __attribute__((ext_vector_type(8))) short bf16x8;
typedef __attribute__((ext_vector_type(4))) float f32x4;
typedef __attribute__((ext_vector_type(2))) float f32x2;

__device__ __forceinline__ unsigned short f2bf(float v) {
    unsigned u = __float_as_uint(v);
    u += 0x7fff + ((u >> 16) & 1);       // round-to-nearest-even
    return (unsigned short)(u >> 16);
}
__device__ __forceinline__ float bf2f(unsigned short s) {
    return __uint_as_float((unsigned)s << 16);
}

// packed f32 VOP3P helpers (CDNA2+: v_pk_{add,mul,fma}_f32)
__device__ __forceinline__ f32x2 pk_add(f32x2 a, f32x2 b) {
    f32x2 d; asm("v_pk_add_f32 %0, %1, %2" : "=v"(d) : "v"(a), "v"(b)); return d;
}
__device__ __forceinline__ f32x2 pk_mul(f32x2 a, f32x2 b) {
    f32x2 d; asm("v_pk_mul_f32 %0, %1, %2" : "=v"(d) : "v"(a), "v"(b)); return d;
}
__device__ __forceinline__ f32x2 pk_fma(f32x2 a, f32x2 b, f32x2 c) {
    f32x2 d; asm("v_pk_fma_f32 %0, %1, %2, %3" : "=v"(d) : "v"(a), "v"(b), "v"(c)); return d;
}

// --------------------------------------------------- split-bf16 conversions
__global__ void convert_x(const float* __restrict__ x, unsigned short* __restrict__ Xh,
                          unsigned short* __restrict__ Xl, int total)
{
    int i = blockIdx.x * 256 + threadIdx.x;
    if (i >= total) return;
    float v = x[i];
    unsigned short hi = f2bf(v);
    unsigned short lo = f2bf(v - bf2f(hi));   // residual is exact in fp32
    Xh[i] = hi; Xl[i] = lo;
}

// W (K x 128) pair -> Wt (256 x K) transposed, split hi/lo. rows 0..127 = Wl cols.
__global__ void convert_w(const float* __restrict__ Wl, const float* __restrict__ Wr,
                          unsigned short* __restrict__ Wth, unsigned short* __restrict__ Wtl,
                          int K)
{
    int t = blockIdx.x * 256 + threadIdx.x;
    if (t >= 256 * K) return;
    int c = t / K, k = t - c * K;
    float v = (c < 128) ? Wl[(size_t)k * 128 + c] : Wr[(size_t)k * 128 + (c - 128)];
    unsigned short hi = f2bf(v);
    unsigned short lo = f2bf(v - bf2f(hi));
    Wth[t] = hi; Wtl[t] = lo;
}

// --------------------------------------------- register-B MFMA dual GEMM
// Tall-skinny GEMM: M=50000, N=256, K<=128. Each wave owns a 32-col tile,
// keeps ALL B fragments in registers (loaded once), streams 64-row tiles
// reading A fragments directly from global. No LDS, no barriers.
template<int K>
__launch_bounds__(256)
__global__ void gemm_reg(const unsigned short* __restrict__ Xh, const unsigned short* __restrict__ Xl,
                         const unsigned short* __restrict__ Wth, const unsigned short* __restrict__ Wtl,
                         const float* __restrict__ bl, const float* __restrict__ br,
                         float* __restrict__ Cl, float* __restrict__ Cr, int n)
{
    constexpr int NCH = K / 32;
    constexpr int RT  = (N_NODES + 63) / 64;   // 782 row tiles
    const int tid  = threadIdx.x;
    const int wave = tid >> 6;
    const int lane = tid & 63;
    const int quad = lane >> 4;
    const int l15  = lane & 15;
    const int wid  = blockIdx.x * 4 + wave;
    const int colid = wid & 7;                 // 8 col tiles of 32
    const int cb32  = colid * 32;              // col in Wt space (0..255)
    const int rs    = wid >> 3;                // row stream
    const int NS    = (gridDim.x * 4) >> 3;

    // B fragments resident: [ch][nt] hi/lo
    bf16x8 Bh[NCH][2], Bo[NCH][2];
    #pragma unroll
    for (int ch = 0; ch < NCH; ch++)
        #pragma unroll
        for (int nt = 0; nt < 2; nt++) {
            const size_t wo = (size_t)(cb32 + nt * 16 + l15) * K + ch * 32 + quad * 8;
            Bh[ch][nt] = *(const bf16x8*)(Wth + wo);
            Bo[ch][nt] = *(const bf16x8*)(Wtl + wo);
        }

    const int cb = cb32 & 127;                 // col within the 128-wide output
    const float* bias = (colid < 4) ? bl : br;
    float* C = (colid < 4) ? Cl : Cr;
    float bv[2];
    bv[0] = bias[cb + l15];
    bv[1] = bias[cb + 16 + l15];

    for (int rt = rs; rt < RT; rt += NS) {
        const int row0 = rt * 64;
        f32x4 acc[4][2];
        #pragma unroll
        for (int mt = 0; mt < 4; mt++) {
            acc[mt][0] = (f32x4){0.f, 0.f, 0.f, 0.f};
            acc[mt][1] = (f32x4){0.f, 0.f, 0.f, 0.f};
        }
        #pragma unroll
        for (int ch = 0; ch < NCH; ch++) {
            bf16x8 ah[4], al[4];
            #pragma unroll
            for (int mt = 0; mt < 4; mt++) {
                int r = row0 + mt * 16 + l15;
                r = (r < n) ? r : (n - 1);     // clamp: garbage rows never stored
                const size_t go = (size_t)r * K + ch * 32 + quad * 8;
                ah[mt] = *(const bf16x8*)(Xh + go);
                al[mt] = *(const bf16x8*)(Xl + go);
            }
            #pragma unroll
            for (int nt = 0; nt < 2; nt++)
                #pragma unroll
                for (int mt = 0; mt < 4; mt++) {
                    acc[mt][nt] = __builtin_amdgcn_mfma_f32_16x16x32_bf16(ah[mt], Bh[ch][nt], acc[mt][nt], 0, 0, 0);
                    acc[mt][nt] = __builtin_amdgcn_mfma_f32_16x16x32_bf16(ah[mt], Bo[ch][nt], acc[mt][nt], 0, 0, 0);
                    acc[mt][nt] = __builtin_amdgcn_mfma_f32_16x16x32_bf16(al[mt], Bh[ch][nt], acc[mt][nt], 0, 0, 0);
                }
        }
        // epilogue: C/D layout col=lane&15, row=quad*4+reg [m89-verified]
        #pragma unroll
        for (int nt = 0; nt < 2; nt++)
            #pragma unroll
            for (int mt = 0; mt < 4; mt++)
                #pragma unroll
                for (int r = 0; r < 4; r++) {
                    const int row = row0 + mt * 16 + quad * 4 + r;
                    if (row < n)
                        C[(size_t)row * 128 + cb + nt * 16 + l15] = acc[mt][nt][r] + bv[nt];
                }
    }
}

// ---------------------------------------------------------------- CSR build
__global__ void deg_hist(const int* __restrict__ dst, int* __restrict__ deg) {
    int e = blockIdx.x * 256 + threadIdx.x;
    if (e < N_EDGES) atomicAdd(&deg[dst[e]], 1);
}

__launch_bounds__(SCAN_B)
__global__ void scan_block(const int* __restrict__ deg, int* __restrict__ rowptr,
                           int* __restrict__ btot)
{
    __shared__ int s[SCAN_B];
    const int tid = threadIdx.x;
    const int i = blockIdx.x * SCAN_B + tid;
    int v = (i < N_NODES) ? deg[i] : 0;
    s[tid] = v;
    __syncthreads();
    for (int off = 1; off < SCAN_B; off <<= 1) {
        int t = (tid >= off) ? s[tid - off] : 0;
        __syncthreads();
        s[tid] += t;
        __syncthreads();
    }
    if (i < N_NODES) rowptr[i] = s[tid] - v;
    if (tid == SCAN_B - 1) btot[blockIdx.x] = s[SCAN_B - 1];
}

__global__ void scan_btot(const int* __restrict__ btot, int* __restrict__ boff) {
    if (threadIdx.x == 0) {
        int a = 0;
        for (int b = 0; b < NB; b++) { boff[b] = a; a += btot[b]; }
        boff[NB] = a;
    }
}

__global__ void scan_add(const int* __restrict__ boff, int* __restrict__ rowptr,
                         int* __restrict__ cursor)
{
    int i = blockIdx.x * 256 + threadIdx.x;
    if (i < N_NODES) {
        int r = rowptr[i] + boff[i >> 10];
        rowptr[i] = r;
        cursor[i] = r;
    }
    if (i == N_NODES) rowptr[N_NODES] = boff[NB];
}

__global__ void scatter_csr(const int* __restrict__ src, const int* __restrict__ dst,
                            int* __restrict__ cursor, int* __restrict__ csr_src)
{
    int e = blockIdx.x * 256 + threadIdx.x;
    if (e >= N_EDGES) return;
    int pos = atomicAdd(&cursor[dst[e]], 1);
    csr_src[pos] = src[e];
}

// graph boundaries from sorted batch: gptr[G+1]
__global__ void build_gptr(const int* __restrict__ batch, int* __restrict__ gptr) {
    int i = blockIdx.x * 256 + threadIdx.x;
    if (i > N_NODES) return;
    if (i == 0) {
        for (int g = 0; g <= batch[0]; g++) gptr[g] = 0;
    } else if (i == N_NODES) {
        for (int g = batch[N_NODES - 1] + 1; g <= GG; g++) gptr[g] = N_NODES;
    } else {
        int b0 = batch[i - 1], b1 = batch[i];
        for (int g = b0 + 1; g <= b1; g++) gptr[g] = i;
    }
}

// ------------------------------------------------- fused per-node attention
// one wave per dst node, FOUR edges in flight (4 groups x 16 lanes, 8 dims/lane).
// PER-HEAD softmax: head = 4-lane cluster; score reduce over xor 1,2 ONLY.
// dim-wise math in packed f32 (v_pk_*). epilogue emits bf16 hi/lo splits.
__launch_bounds__(256)
__global__ void node_attn(const float* __restrict__ xl, const float* __restrict__ xr,
                          const int* __restrict__ rowptr, const int* __restrict__ csr_src,
                          const float* __restrict__ att, const float* __restrict__ bvec,
                          unsigned short* __restrict__ Hh, unsigned short* __restrict__ Hl)
{
    const int node = (blockIdx.x * 256 + threadIdx.x) >> 6;
    const int lane = threadIdx.x & 63;
    if (node >= N_NODES) return;
    const int grp = lane >> 4;     // 4 edge slots
    const int li  = lane & 15;     // 16 lanes per edge, 8 dims each; head = li>>2

    const size_t nb = (size_t)node * HD + li * 8;
    f32x2 xrp[4], awp[4];
    {
        const float4 a = *(const float4*)(xr + nb);
        const float4 b = *(const float4*)(xr + nb + 4);
        xrp[0] = (f32x2){a.x, a.y}; xrp[1] = (f32x2){a.z, a.w};
        xrp[2] = (f32x2){b.x, b.y}; xrp[3] = (f32x2){b.z, b.w};
        const float4 c = *(const float4*)(att + li * 8);
        const float4 d = *(const float4*)(att + li * 8 + 4);
        awp[0] = (f32x2){c.x, c.y}; awp[1] = (f32x2){c.z, c.w};
        awp[2] = (f32x2){d.x, d.y}; awp[3] = (f32x2){d.z, d.w};
    }
    const f32x2 nsl = (f32x2){NEG_SLOPE, NEG_SLOPE};
    const int beg = rowptr[node];
    const int end = rowptr[node + 1];

    float m = -1e30f, l = 0.f;
    f32x2 accp[4];
    #pragma unroll
    for (int j = 0; j < 4; j++) accp[j] = (f32x2){0.f, 0.f};

    // prologue gather
    f32x2 vp[4];
    {
        const int e0 = beg + grp;
        const int s0 = (e0 < end) ? csr_src[e0] : 0;
        const float4 a = *(const float4*)(xl + (size_t)s0 * HD + li * 8);
        const float4 b = *(const float4*)(xl + (size_t)s0 * HD + li * 8 + 4);
        vp[0] = (f32x2){a.x, a.y}; vp[1] = (f32x2){a.z, a.w};
        vp[2] = (f32x2){b.x, b.y}; vp[3] = (f32x2){b.z, b.w};
    }

    for (int base = beg; base < end; base += 4) {
        const bool valid = (base + grp) < end;
        f32x2 np[4];
        #pragma unroll
        for (int j = 0; j < 4; j++) np[j] = vp[j];
        if (base + 4 < end) {
            const int e2 = base + 4 + grp;
            const int s2 = (e2 < end) ? csr_src[e2] : 0;
            const float4 a = *(const float4*)(xl + (size_t)s2 * HD + li * 8);
            const float4 b = *(const float4*)(xl + (size_t)s2 * HD + li * 8 + 4);
            np[0] = (f32x2){a.x, a.y}; np[1] = (f32x2){a.z, a.w};
            np[2] = (f32x2){b.x, b.y}; np[3] = (f32x2){b.z, b.w};
        }
        // leaky_relu(v + xr) . att (packed): leaky = max(t, 0.2t)
        f32x2 pd = (f32x2){0.f, 0.f};
        #pragma unroll
        for (int j = 0; j < 4; j++) {
            f32x2 t = pk_add(vp[j], xrp[j]);
            f32x2 u = pk_mul(t, nsl);
            t[0] = fmaxf(t[0], u[0]);
            t[1] = fmaxf(t[1], u[1]);
            pd = pk_fma(t, awp[j], pd);
        }
        float p = pd[0] + pd[1];
        // per-head score: 4-lane cluster (32 dims) -> xor 1,2 only
        p += __shfl_xor(p, 1);
        p += __shfl_xor(p, 2);

        const float mn = valid ? fmaxf(m, p) : m;
        const float w  = valid ? __expf(p - mn) : 0.f;
        const float sc = __expf(m - mn);
        l = fmaf(l, sc, w);
        const f32x2 w2  = (f32x2){w, w};
        const f32x2 sc2 = (f32x2){sc, sc};
        #pragma unroll
        for (int j = 0; j < 4; j++) {
            accp[j] = pk_fma(accp[j], sc2, pk_mul(w2, vp[j]));
            vp[j] = np[j];
        }
        m = mn;
    }

    // cross-group merge (xor 16, then 32): same li (same head/dims), different group
    #pragma unroll
    for (int off = 16; off < 64; off <<= 1) {
        const float mo = __shfl_xor(m, off);
        const float lo = __shfl_xor(l, off);
        f32x2 bo[4];
        #pragma unroll
        for (int j = 0; j < 4; j++) {
            bo[j][0] = __shfl_xor(accp[j][0], off);
            bo[j][1] = __shfl_xor(accp[j][1], off);
        }
        const float mm = fmaxf(m, mo);
        const float e1 = __expf(m - mm);
        const float e2 = __expf(mo - mm);
        l = l * e1 + lo * e2;
        const f32x2 e1p = (f32x2){e1, e1};
        const f32x2 e2p = (f32x2){e2, e2};
        #pragma unroll
        for (int j = 0; j < 4; j++)
            accp[j] = pk_fma(accp[j], e1p, pk_mul(bo[j], e2p));
        m = mm;
    }

    if (grp == 0) {
        const float inv = (l > 0.f) ? 1.f / l : 0.f;   // per-head l (per lane)
        const float4 bb0 = *(const float4*)(bvec + li * 8);
        const float4 bb1 = *(const float4*)(bvec + li * 8 + 4);
        float o[8];
        o[0] = fmaf(accp[0][0], inv, bb0.x);
        o[1] = fmaf(accp[0][1], inv, bb0.y);
        o[2] = fmaf(accp[1][0], inv, bb0.z);
        o[3] = fmaf(accp[1][1], inv, bb0.w);
        o[4] = fmaf(accp[2][0], inv, bb1.x);
        o[5] = fmaf(accp[2][1], inv, bb1.y);
        o[6] = fmaf(accp[3][0], inv, bb1.z);
        o[7] = fmaf(accp[3][1], inv, bb1.w);
        bf16x8 hv, lv;
        #pragma unroll
        for (int j = 0; j < 8; j++) {
            float e = (o[j] > 0.f) ? o[j] : expm1f(o[j]);
            unsigned short h = f2bf(e);
            hv[j] = (short)h;
            lv[j] = (short)f2bf(e - bf2f(h));
        }
        *(bf16x8*)(Hh + nb) = hv;
        *(bf16x8*)(Hl + nb) = lv;
    }
}

// ------------------------------------------ fused mean-pool + linear head
__launch_bounds__(256)
__global__ void pool_head(const unsigned short* __restrict__ Hh, const unsigned short* __restrict__ Hl,
                          const int* __restrict__ gptr, const float* __restrict__ Wh,
                          const float* __restrict__ bh, float* __restrict__ out)
{
    const int g = (blockIdx.x * 256 + threadIdx.x) >> 6;
    const int lane = threadIdx.x & 63;
    if (g >= GG) return;
    const int b0 = gptr[g], b1 = gptr[g + 1];
    const float2 w = *(const float2*)(Wh + lane * 2);
    float sx = 0.f, sy = 0.f;
    for (int i = b0; i < b1; i++) {
        const unsigned vh = *(const unsigned*)(Hh + (size_t)i * HD + lane * 2);
        const unsigned vl = *(const unsigned*)(Hl + (size_t)i * HD + lane * 2);
        sx += bf2f((unsigned short)(vh & 0xffff)) + bf2f((unsigned short)(vl & 0xffff));
        sy += bf2f((unsigned short)(vh >> 16))    + bf2f((unsigned short)(vl >> 16));
    }
    float d = sx * w.x + sy * w.y;
    d += __shfl_xor(d, 1);
    d += __shfl_xor(d, 2);
    d += __shfl_xor(d, 4);
    d += __shfl_xor(d, 8);
    d += __shfl_xor(d, 16);
    d += __shfl_xor(d, 32);
    if (lane == 0) out[g] = d / fmaxf((float)(b1 - b0), 1.f) + bh[0];
}

// ---------------------------------------------------------------- launch
extern "C" void kernel_launch(void* const* d_in, const int* in_sizes, int n_in,
                              void* d_out, int out_size, void* d_ws, size_t ws_size,
                              hipStream_t stream)
{
    const float* x     = (const float*)d_in[0];
    const int*   edge  = (const int*)d_in[1];
    const int*   batch = (const int*)d_in[2];
    const int*   src   = edge;
    const int*   dst   = edge + N_EDGES;
    const float* Wh    = (const float*)d_in[21];
    const float* bh    = (const float*)d_in[22];
    float* out = (float*)d_out;

    const size_t N128 = (size_t)N_NODES * HD;
    float* buf_xl = (float*)d_ws;                       // N*128 f32
    float* buf_xr = buf_xl + N128;                      // N*128 f32
    unsigned short* Xh  = (unsigned short*)(buf_xr + N128);   // N*128 bf16
    unsigned short* Xl_ = Xh + N128;                    // N*128 bf16
    unsigned short* Wth = Xl_ + N128;                   // 3 * 256*128 bf16
    unsigned short* Wtl = Wth + 3 * 256 * 128;          // 3 * 256*128 bf16
    int* deg     = (int*)(Wtl + 3 * 256 * 128);         // N
    int* rowptr  = deg + N_NODES;                       // N+1
    int* cursor  = rowptr + N_NODES + 1;                // N
    int* csr_src = cursor + N_NODES;                    // E
    int* btot    = csr_src + N_EDGES;                   // NB
    int* boff    = btot + NB;                           // NB+1
    int* gptr    = boff + NB + 1;                       // G+1

    // ---- CSR + graph-boundary build (layer-invariant)
    hipMemsetAsync(deg, 0, (size_t)N_NODES * sizeof(int), stream);
    deg_hist<<<(N_EDGES + 255) / 256, 256, 0, stream>>>(dst, deg);
    scan_block<<<NB, SCAN_B, 0, stream>>>(deg, rowptr, btot);
    scan_btot<<<1, 64, 0, stream>>>(btot, boff);
    scan_add<<<(N_NODES + 256) / 256, 256, 0, stream>>>(boff, rowptr, cursor);
    scatter_csr<<<(N_EDGES + 255) / 256, 256, 0, stream>>>(src, dst, cursor, csr_src);
    build_gptr<<<(N_NODES + 256) / 256, 256, 0, stream>>>(batch, gptr);

    // ---- weight + input split-bf16 conversion
    convert_x<<<(N_NODES * 64 + 255) / 256, 256, 0, stream>>>(x, Xh, Xl_, N_NODES * 64);
    for (int l = 0; l < 3; l++) {
        const int K = (l == 0) ? 64 : 128;
        convert_w<<<(256 * K + 255) / 256, 256, 0, stream>>>(
            (const float*)d_in[3 + 6 * l], (const float*)d_in[5 + 6 * l],
            Wth + l * 256 * 128, Wtl + l * 256 * 128, K);
    }

    // gemm grid: 522 blocks -> 2088 waves = 8 col-tiles x 261 row streams
    const int gemm_grid = 522;
    const int attn_grid = (N_NODES + 3) / 4;

    for (int l = 0; l < 3; l++) {
        const float* bl  = (const float*)d_in[4 + 6 * l];
        const float* br  = (const float*)d_in[6 + 6 * l];
        const float* att = (const float*)d_in[7 + 6 * l];
        const float* bb  = (const float*)d_in[8 + 6 * l];

        if (l == 0)
            gemm_reg<64><<<gemm_grid, 256, 0, stream>>>(Xh, Xl_, Wth, Wtl,
                                                        bl, br, buf_xl, buf_xr, N_NODES);
        else
            gemm_reg<128><<<gemm_grid, 256, 0, stream>>>(Xh, Xl_,
                                                         Wth + l * 256 * 128, Wtl + l * 256 * 128,
                                                         bl, br, buf_xl, buf_xr, N_NODES);
        node_attn<<<attn_grid, 256, 0, stream>>>(buf_xl, buf_xr, rowptr, csr_src,
                                                 att, bb, Xh, Xl_);
    }

    pool_head<<<GG / 4, 256, 0, stream>>>(Xh, Xl_, gptr, Wh, bh, out);
}

// Round 5
// 514.246 us; speedup vs baseline: 1.0516x; 1.0516x over previous
//
#include <hip/hip_runtime.h>
#include <math.h>

#define N_NODES 50000
#define N_EDGES 800000
#define HD 128          // H*D = 4*32
#define GG 1024
#define NEG_SLOPE 0.2f
#define SCAN_B 1024
#define NB ((N_NODES + SCAN_B - 1) / SCAN_B)   // 49
#define LOG2E 1.4426950408889634f

#if __has_builtin(__builtin_amdgcn_exp2f)
#define EXP2F(x) __builtin_amdgcn_exp2f(x)
#else
#define EXP2F(x) exp2f(x)
#endif

typedef __attribute__((ext_vector_type(8))) short bf16x8;
typedef __attribute__((ext_vector_type(4))) float f32x4;

__device__ __forceinline__ unsigned short f2bf(float v) {
    unsigned u = __float_as_uint(v);
    u += 0x7fff + ((u >> 16) & 1);       // round-to-nearest-even
    return (unsigned short)(u >> 16);
}
__device__ __forceinline__ float bf2f(unsigned short s) {
    return __uint_as_float((unsigned)s << 16);
}

// --------------------------------------------------- split-bf16 conversions
__global__ void convert_x(const float* __restrict__ x, unsigned short* __restrict__ Xh,
                          unsigned short* __restrict__ Xl, int total)
{
    int i = blockIdx.x * 256 + threadIdx.x;
    if (i >= total) return;
    float v = x[i];
    unsigned short hi = f2bf(v);
    unsigned short lo = f2bf(v - bf2f(hi));   // residual is exact in fp32
    Xh[i] = hi; Xl[i] = lo;
}

// all 3 layers' W (K x 128) pairs -> Wt (256 x K) transposed, split hi/lo, one kernel.
// layer l output at l*256*128. rows 0..127 = Wl cols, 128..255 = Wr cols.
__global__ void convert_w_all(const float* __restrict__ W0l, const float* __restrict__ W0r,
                              const float* __restrict__ W1l, const float* __restrict__ W1r,
                              const float* __restrict__ W2l, const float* __restrict__ W2r,
                              unsigned short* __restrict__ Wth, unsigned short* __restrict__ Wtl)
{
    const int t = blockIdx.x * 256 + threadIdx.x;
    const float* Wl; const float* Wr;
    int c, k, o;
    if (t < 16384) {                       // layer 0, K=64
        c = t >> 6; k = t & 63; o = t;
        Wl = W0l; Wr = W0r;
    } else if (t < 49152) {                // layer 1, K=128
        const int b = t - 16384; c = b >> 7; k = b & 127; o = 32768 + b;
        Wl = W1l; Wr = W1r;
    } else if (t < 81920) {                // layer 2, K=128
        const int b = t - 49152; c = b >> 7; k = b & 127; o = 65536 + b;
        Wl = W2l; Wr = W2r;
    } else return;
    const float v = (c < 128) ? Wl[(size_t)k * 128 + c] : Wr[(size_t)k * 128 + (c - 128)];
    const unsigned short hi = f2bf(v);
    Wth[o] = hi;
    Wtl[o] = f2bf(v - bf2f(hi));
}

// --------------------------------------------- register-B MFMA dual GEMM
// Tall-skinny GEMM: M=50000, N=256, K<=128. Each wave owns a 32-col tile,
// keeps ALL B fragments in registers (loaded once), streams 64-row tiles
// reading A fragments directly from global. No LDS, no barriers.
template<int K>
__launch_bounds__(256)
__global__ void gemm_reg(const unsigned short* __restrict__ Xh, const unsigned short* __restrict__ Xl,
                         const unsigned short* __restrict__ Wth, const unsigned short* __restrict__ Wtl,
                         const float* __restrict__ bl, const float* __restrict__ br,
                         float* __restrict__ Cl, float* __restrict__ Cr, int n)
{
    constexpr int NCH = K / 32;
    constexpr int RT  = (N_NODES + 63) / 64;   // 782 row tiles
    const int tid  = threadIdx.x;
    const int wave = tid >> 6;
    const int lane = tid & 63;
    const int quad = lane >> 4;
    const int l15  = lane & 15;
    const int wid  = blockIdx.x * 4 + wave;
    const int colid = wid & 7;                 // 8 col tiles of 32
    const int cb32  = colid * 32;              // col in Wt space (0..255)
    const int rs    = wid >> 3;                // row stream
    const int NS    = (gridDim.x * 4) >> 3;

    // B fragments resident: [ch][nt] hi/lo
    bf16x8 Bh[NCH][2], Bo[NCH][2];
    #pragma unroll
    for (int ch = 0; ch < NCH; ch++)
        #pragma unroll
        for (int nt = 0; nt < 2; nt++) {
            const size_t wo = (size_t)(cb32 + nt * 16 + l15) * K + ch * 32 + quad * 8;
            Bh[ch][nt] = *(const bf16x8*)(Wth + wo);
            Bo[ch][nt] = *(const bf16x8*)(Wtl + wo);
        }

    const int cb = cb32 & 127;                 // col within the 128-wide output
    const float* bias = (colid < 4) ? bl : br;
    float* C = (colid < 4) ? Cl : Cr;
    float bv[2];
    bv[0] = bias[cb + l15];
    bv[1] = bias[cb + 16 + l15];

    for (int rt = rs; rt < RT; rt += NS) {
        const int row0 = rt * 64;
        f32x4 acc[4][2];
        #pragma unroll
        for (int mt = 0; mt < 4; mt++) {
            acc[mt][0] = (f32x4){0.f, 0.f, 0.f, 0.f};
            acc[mt][1] = (f32x4){0.f, 0.f, 0.f, 0.f};
        }
        #pragma unroll
        for (int ch = 0; ch < NCH; ch++) {
            bf16x8 ah[4], al[4];
            #pragma unroll
            for (int mt = 0; mt < 4; mt++) {
                int r = row0 + mt * 16 + l15;
                r = (r < n) ? r : (n - 1);     // clamp: garbage rows never stored
                const size_t go = (size_t)r * K + ch * 32 + quad * 8;
                ah[mt] = *(const bf16x8*)(Xh + go);
                al[mt] = *(const bf16x8*)(Xl + go);
            }
            #pragma unroll
            for (int nt = 0; nt < 2; nt++)
                #pragma unroll
                for (int mt = 0; mt < 4; mt++) {
                    acc[mt][nt] = __builtin_amdgcn_mfma_f32_16x16x32_bf16(ah[mt], Bh[ch][nt], acc[mt][nt], 0, 0, 0);
                    acc[mt][nt] = __builtin_amdgcn_mfma_f32_16x16x32_bf16(ah[mt], Bo[ch][nt], acc[mt][nt], 0, 0, 0);
                    acc[mt][nt] = __builtin_amdgcn_mfma_f32_16x16x32_bf16(al[mt], Bh[ch][nt], acc[mt][nt], 0, 0, 0);
                }
        }
        // epilogue: C/D layout col=lane&15, row=quad*4+reg [m89-verified]
        #pragma unroll
        for (int nt = 0; nt < 2; nt++)
            #pragma unroll
            for (int mt = 0; mt < 4; mt++)
                #pragma unroll
                for (int r = 0; r < 4; r++) {
                    const int row = row0 + mt * 16 + quad * 4 + r;
                    if (row < n)
                        C[(size_t)row * 128 + cb + nt * 16 + l15] = acc[mt][nt][r] + bv[nt];
                }
    }
}

// ---------------------------------------------------------------- CSR build
__global__ void deg_hist(const int* __restrict__ dst, int* __restrict__ deg) {
    int e = blockIdx.x * 256 + threadIdx.x;
    if (e < N_EDGES) atomicAdd(&deg[dst[e]], 1);
}

__launch_bounds__(SCAN_B)
__global__ void scan_block(const int* __restrict__ deg, int* __restrict__ rowptr,
                           int* __restrict__ btot)
{
    __shared__ int s[SCAN_B];
    const int tid = threadIdx.x;
    const int i = blockIdx.x * SCAN_B + tid;
    int v = (i < N_NODES) ? deg[i] : 0;
    s[tid] = v;
    __syncthreads();
    for (int off = 1; off < SCAN_B; off <<= 1) {
        int t = (tid >= off) ? s[tid - off] : 0;
        __syncthreads();
        s[tid] += t;
        __syncthreads();
    }
    if (i < N_NODES) rowptr[i] = s[tid] - v;
    if (tid == SCAN_B - 1) btot[blockIdx.x] = s[SCAN_B - 1];
}

// scan_add now also does the 49-block prefix scan (no serial scan_btot kernel)
__launch_bounds__(256)
__global__ void scan_add(const int* __restrict__ btot, int* __restrict__ rowptr,
                         int* __restrict__ cursor)
{
    __shared__ int sb[NB + 1];
    const int tid = threadIdx.x;
    if (tid < 64) {
        const int v = (tid < NB) ? btot[tid] : 0;
        int incl = v;
        #pragma unroll
        for (int off = 1; off < 64; off <<= 1) {
            const int t = __shfl_up(incl, off);
            if (tid >= off) incl += t;
        }
        if (tid < NB) sb[tid] = incl - v;      // exclusive prefix
        if (tid == NB - 1) sb[NB] = incl;      // total
    }
    __syncthreads();
    const int i = blockIdx.x * 256 + tid;
    if (i < N_NODES) {
        const int r = rowptr[i] + sb[i >> 10];
        rowptr[i] = r;
        cursor[i] = r;
    }
    if (i == N_NODES) rowptr[N_NODES] = sb[NB];
}

__global__ void scatter_csr(const int* __restrict__ src, const int* __restrict__ dst,
                            int* __restrict__ cursor, int* __restrict__ csr_src)
{
    int e = blockIdx.x * 256 + threadIdx.x;
    if (e >= N_EDGES) return;
    int pos = atomicAdd(&cursor[dst[e]], 1);
    csr_src[pos] = src[e];
}

// graph boundaries from sorted batch: gptr[G+1]
__global__ void build_gptr(const int* __restrict__ batch, int* __restrict__ gptr) {
    int i = blockIdx.x * 256 + threadIdx.x;
    if (i > N_NODES) return;
    if (i == 0) {
        for (int g = 0; g <= batch[0]; g++) gptr[g] = 0;
    } else if (i == N_NODES) {
        for (int g = batch[N_NODES - 1] + 1; g <= GG; g++) gptr[g] = N_NODES;
    } else {
        int b0 = batch[i - 1], b1 = batch[i];
        for (int g = b0 + 1; g <= b1; g++) gptr[g] = i;
    }
}

// ------------------------------------------------- fused per-node attention
// one wave per dst node, FOUR edges in flight (4 groups x 16 lanes, 8 dims/lane).
// PER-HEAD softmax: head = 4-lane cluster; score reduce over xor 1,2 ONLY.
// exp2-domain (att pre-scaled by log2e); defer-max rescale skip (THR=8).
__launch_bounds__(256)
__global__ void node_attn(const float* __restrict__ xl, const float* __restrict__ xr,
                          const int* __restrict__ rowptr, const int* __restrict__ csr_src,
                          const float* __restrict__ att, const float* __restrict__ bvec,
                          unsigned short* __restrict__ Hh, unsigned short* __restrict__ Hl)
{
    const int node = (blockIdx.x * 256 + threadIdx.x) >> 6;
    const int lane = threadIdx.x & 63;
    if (node >= N_NODES) return;
    const int grp = lane >> 4;     // 4 edge slots
    const int li  = lane & 15;     // 16 lanes per edge, 8 dims each; head = li>>2

    const size_t nb = (size_t)node * HD + li * 8;
    const float4 xr0 = *(const float4*)(xr + nb);
    const float4 xr1 = *(const float4*)(xr + nb + 4);
    float4 aw0 = *(const float4*)(att + li * 8);
    float4 aw1 = *(const float4*)(att + li * 8 + 4);
    aw0.x *= LOG2E; aw0.y *= LOG2E; aw0.z *= LOG2E; aw0.w *= LOG2E;
    aw1.x *= LOG2E; aw1.y *= LOG2E; aw1.z *= LOG2E; aw1.w *= LOG2E;
    const int beg = rowptr[node];
    const int end = rowptr[node + 1];

    float m = -1e30f, l = 0.f;
    float4 a0 = make_float4(0.f, 0.f, 0.f, 0.f);
    float4 a1 = make_float4(0.f, 0.f, 0.f, 0.f);

    // prologue gather
    int e0 = beg + grp;
    int s0 = (e0 < end) ? csr_src[e0] : 0;
    float4 v0 = *(const float4*)(xl + (size_t)s0 * HD + li * 8);
    float4 v1 = *(const float4*)(xl + (size_t)s0 * HD + li * 8 + 4);

    for (int base = beg; base < end; base += 4) {
        const bool valid = (base + grp) < end;
        float4 n0 = v0, n1 = v1;
        if (base + 4 < end) {
            const int e2 = base + 4 + grp;
            const int s2 = (e2 < end) ? csr_src[e2] : 0;
            n0 = *(const float4*)(xl + (size_t)s2 * HD + li * 8);
            n1 = *(const float4*)(xl + (size_t)s2 * HD + li * 8 + 4);
        }
        // score (log2 domain): leaky = max(t, 0.2t)
        float t, p;
        t = v0.x + xr0.x; t = fmaxf(t, NEG_SLOPE * t); p  = t * aw0.x;
        t = v0.y + xr0.y; t = fmaxf(t, NEG_SLOPE * t); p  = fmaf(t, aw0.y, p);
        t = v0.z + xr0.z; t = fmaxf(t, NEG_SLOPE * t); p  = fmaf(t, aw0.z, p);
        t = v0.w + xr0.w; t = fmaxf(t, NEG_SLOPE * t); p  = fmaf(t, aw0.w, p);
        t = v1.x + xr1.x; t = fmaxf(t, NEG_SLOPE * t); p  = fmaf(t, aw1.x, p);
        t = v1.y + xr1.y; t = fmaxf(t, NEG_SLOPE * t); p  = fmaf(t, aw1.y, p);
        t = v1.z + xr1.z; t = fmaxf(t, NEG_SLOPE * t); p  = fmaf(t, aw1.z, p);
        t = v1.w + xr1.w; t = fmaxf(t, NEG_SLOPE * t); p  = fmaf(t, aw1.w, p);
        // per-head score: 4-lane cluster (32 dims) -> xor 1,2 only
        p += __shfl_xor(p, 1);
        p += __shfl_xor(p, 2);

        const bool grow = valid && (p > m + 8.f);
        if (__any(grow)) {
            // rescale path (rare after first edges)
            const float mn = valid ? fmaxf(m, p) : m;
            const float sc = EXP2F(m - mn);
            const float w  = valid ? EXP2F(p - mn) : 0.f;
            l = fmaf(l, sc, w);
            a0.x = fmaf(a0.x, sc, w * v0.x);
            a0.y = fmaf(a0.y, sc, w * v0.y);
            a0.z = fmaf(a0.z, sc, w * v0.z);
            a0.w = fmaf(a0.w, sc, w * v0.w);
            a1.x = fmaf(a1.x, sc, w * v1.x);
            a1.y = fmaf(a1.y, sc, w * v1.y);
            a1.z = fmaf(a1.z, sc, w * v1.z);
            a1.w = fmaf(a1.w, sc, w * v1.w);
            m = mn;
        } else {
            // skip path: weights bounded by 2^8
            const float w = valid ? EXP2F(p - m) : 0.f;
            l += w;
            a0.x = fmaf(w, v0.x, a0.x);
            a0.y = fmaf(w, v0.y, a0.y);
            a0.z = fmaf(w, v0.z, a0.z);
            a0.w = fmaf(w, v0.w, a0.w);
            a1.x = fmaf(w, v1.x, a1.x);
            a1.y = fmaf(w, v1.y, a1.y);
            a1.z = fmaf(w, v1.z, a1.z);
            a1.w = fmaf(w, v1.w, a1.w);
        }
        v0 = n0; v1 = n1;
    }

    // cross-group merge (xor 16, then 32): same li (same head/dims), different group
    #pragma unroll
    for (int off = 16; off < 64; off <<= 1) {
        const float mo = __shfl_xor(m, off);
        const float lo = __shfl_xor(l, off);
        float4 b0, b1;
        b0.x = __shfl_xor(a0.x, off); b0.y = __shfl_xor(a0.y, off);
        b0.z = __shfl_xor(a0.z, off); b0.w = __shfl_xor(a0.w, off);
        b1.x = __shfl_xor(a1.x, off); b1.y = __shfl_xor(a1.y, off);
        b1.z = __shfl_xor(a1.z, off); b1.w = __shfl_xor(a1.w, off);
        const float mm = fmaxf(m, mo);
        const float e1 = EXP2F(m - mm);
        const float e2 = EXP2F(mo - mm);
        l = l * e1 + lo * e2;
        a0.x = a0.x * e1 + b0.x * e2;
        a0.y = a0.y * e1 + b0.y * e2;
        a0.z = a0.z * e1 + b0.z * e2;
        a0.w = a0.w * e1 + b0.w * e2;
        a1.x = a1.x * e1 + b1.x * e2;
        a1.y = a1.y * e1 + b1.y * e2;
        a1.z = a1.z * e1 + b1.z * e2;
        a1.w = a1.w * e1 + b1.w * e2;
        m = mm;
    }

    if (grp == 0) {
        const float inv = (l > 0.f) ? 1.f / l : 0.f;   // per-head l (per lane)
        const float4 bb0 = *(const float4*)(bvec + li * 8);
        const float4 bb1 = *(const float4*)(bvec + li * 8 + 4);
        float o[8];
        o[0] = fmaf(a0.x, inv, bb0.x);
        o[1] = fmaf(a0.y, inv, bb0.y);
        o[2] = fmaf(a0.z, inv, bb0.z);
        o[3] = fmaf(a0.w, inv, bb0.w);
        o[4] = fmaf(a1.x, inv, bb1.x);
        o[5] = fmaf(a1.y, inv, bb1.y);
        o[6] = fmaf(a1.z, inv, bb1.z);
        o[7] = fmaf(a1.w, inv, bb1.w);
        bf16x8 hv, lv;
        #pragma unroll
        for (int j = 0; j < 8; j++) {
            float e = (o[j] > 0.f) ? o[j] : expm1f(o[j]);
            unsigned short h = f2bf(e);
            hv[j] = (short)h;
            lv[j] = (short)f2bf(e - bf2f(h));
        }
        *(bf16x8*)(Hh + nb) = hv;
        *(bf16x8*)(Hl + nb) = lv;
    }
}

// ------------------------------------------ fused mean-pool + linear head
__launch_bounds__(256)
__global__ void pool_head(const unsigned short* __restrict__ Hh, const unsigned short* __restrict__ Hl,
                          const int* __restrict__ gptr, const float* __restrict__ Wh,
                          const float* __restrict__ bh, float* __restrict__ out)
{
    const int g = (blockIdx.x * 256 + threadIdx.x) >> 6;
    const int lane = threadIdx.x & 63;
    if (g >= GG) return;
    const int b0 = gptr[g], b1 = gptr[g + 1];
    const float2 w = *(const float2*)(Wh + lane * 2);
    float sx = 0.f, sy = 0.f;
    for (int i = b0; i < b1; i++) {
        const unsigned vh = *(const unsigned*)(Hh + (size_t)i * HD + lane * 2);
        const unsigned vl = *(const unsigned*)(Hl + (size_t)i * HD + lane * 2);
        sx += bf2f((unsigned short)(vh & 0xffff)) + bf2f((unsigned short)(vl & 0xffff));
        sy += bf2f((unsigned short)(vh >> 16))    + bf2f((unsigned short)(vl >> 16));
    }
    float d = sx * w.x + sy * w.y;
    d += __shfl_xor(d, 1);
    d += __shfl_xor(d, 2);
    d += __shfl_xor(d, 4);
    d += __shfl_xor(d, 8);
    d += __shfl_xor(d, 16);
    d += __shfl_xor(d, 32);
    if (lane == 0) out[g] = d / fmaxf((float)(b1 - b0), 1.f) + bh[0];
}

// ---------------------------------------------------------------- launch
extern "C" void kernel_launch(void* const* d_in, const int* in_sizes, int n_in,
                              void* d_out, int out_size, void* d_ws, size_t ws_size,
                              hipStream_t stream)
{
    const float* x     = (const float*)d_in[0];
    const int*   edge  = (const int*)d_in[1];
    const int*   batch = (const int*)d_in[2];
    const int*   src   = edge;
    const int*   dst   = edge + N_EDGES;
    const float* Wh    = (const float*)d_in[21];
    const float* bh    = (const float*)d_in[22];
    float* out = (float*)d_out;

    const size_t N128 = (size_t)N_NODES * HD;
    float* buf_xl = (float*)d_ws;                       // N*128 f32
    float* buf_xr = buf_xl + N128;                      // N*128 f32
    unsigned short* Xh  = (unsigned short*)(buf_xr + N128);   // N*128 bf16
    unsigned short* Xl_ = Xh + N128;                    // N*128 bf16
    unsigned short* Wth = Xl_ + N128;                   // 3 * 256*128 bf16
    unsigned short* Wtl = Wth + 3 * 256 * 128;          // 3 * 256*128 bf16
    int* deg     = (int*)(Wtl + 3 * 256 * 128);         // N
    int* rowptr  = deg + N_NODES;                       // N+1
    int* cursor  = rowptr + N_NODES + 1;                // N
    int* csr_src = cursor + N_NODES;                    // E
    int* btot    = csr_src + N_EDGES;                   // NB
    int* boff    = btot + NB;                           // NB+1 (unused now)
    int* gptr    = boff + NB + 1;                       // G+1

    // ---- CSR + graph-boundary build (layer-invariant)
    hipMemsetAsync(deg, 0, (size_t)N_NODES * sizeof(int), stream);
    deg_hist<<<(N_EDGES + 255) / 256, 256, 0, stream>>>(dst, deg);
    scan_block<<<NB, SCAN_B, 0, stream>>>(deg, rowptr, btot);
    scan_add<<<(N_NODES + 256) / 256, 256, 0, stream>>>(btot, rowptr, cursor);
    scatter_csr<<<(N_EDGES + 255) / 256, 256, 0, stream>>>(src, dst, cursor, csr_src);
    build_gptr<<<(N_NODES + 256) / 256, 256, 0, stream>>>(batch, gptr);

    // ---- weight + input split-bf16 conversion
    convert_x<<<(N_NODES * 64 + 255) / 256, 256, 0, stream>>>(x, Xh, Xl_, N_NODES * 64);
    convert_w_all<<<320, 256, 0, stream>>>(
        (const float*)d_in[3], (const float*)d_in[5],
        (const float*)d_in[9], (const float*)d_in[11],
        (const float*)d_in[15], (const float*)d_in[17],
        Wth, Wtl);

    // gemm grid: 768 blocks -> 3072 waves = 8 col-tiles x 384 row streams
    const int gemm_grid = 768;
    const int attn_grid = (N_NODES + 3) / 4;

    for (int l = 0; l < 3; l++) {
        const float* bl  = (const float*)d_in[4 + 6 * l];
        const float* br  = (const float*)d_in[6 + 6 * l];
        const float* att = (const float*)d_in[7 + 6 * l];
        const float* bb  = (const float*)d_in[8 + 6 * l];

        if (l == 0)
            gemm_reg<64><<<gemm_grid, 256, 0, stream>>>(Xh, Xl_, Wth, Wtl,
                                                        bl, br, buf_xl, buf_xr, N_NODES);
        else
            gemm_reg<128><<<gemm_grid, 256, 0, stream>>>(Xh, Xl_,
                                                         Wth + l * 256 * 128, Wtl + l * 256 * 128,
                                                         bl, br, buf_xl, buf_xr, N_NODES);
        node_attn<<<attn_grid, 256, 0, stream>>>(buf_xl, buf_xr, rowptr, csr_src,
                                                 att, bb, Xh, Xl_);
    }

    pool_head<<<GG / 4, 256, 0, stream>>>(Xh, Xl_, gptr, Wh, bh, out);
}